// Round 2
// baseline (404.854 us; speedup 1.0000x reference)
//
#include <hip/hip_runtime.h>
#include <hip/hip_bf16.h>

#define N_NODES 50000
#define N_EDGES 800000
#define F_IN 32
#define CELL_DIM 16
#define D_IN 48      // F_IN + CELL_DIM
#define C_DIM 64
#define X_STRIDE 33  // F_IN + 1 (cell id column)
#define NUM_CELLS 854
#define NEG_SLOPE 0.2f
#define SCAN_BLOCKS 49  // ceil(50000/1024)

// ---------------- CSR build ----------------

__global__ __launch_bounds__(256) void k_hist(const int* __restrict__ ei, int* __restrict__ deg) {
  int e = blockIdx.x * 256 + threadIdx.x;
  if (e < N_EDGES) atomicAdd(&deg[ei[N_EDGES + e]], 1);
}

__global__ __launch_bounds__(1024) void k_scan1(const int* __restrict__ deg, int* __restrict__ off,
                                                int* __restrict__ bsum) {
  __shared__ int s[1024];
  int i = blockIdx.x * 1024 + threadIdx.x;
  int v = (i < N_NODES) ? deg[i] : 0;
  s[threadIdx.x] = v;
  __syncthreads();
  for (int o = 1; o < 1024; o <<= 1) {
    int t = (threadIdx.x >= (unsigned)o) ? s[threadIdx.x - o] : 0;
    __syncthreads();
    s[threadIdx.x] += t;
    __syncthreads();
  }
  if (i < N_NODES) off[i] = s[threadIdx.x] - v;  // block-local exclusive
  if (threadIdx.x == 1023) bsum[blockIdx.x] = s[1023];
}

__global__ __launch_bounds__(64) void k_scan2(int* __restrict__ bsum) {
  int lane = threadIdx.x;
  int v = (lane < SCAN_BLOCKS) ? bsum[lane] : 0;
  int orig = v;
  for (int o = 1; o < 64; o <<= 1) {
    int t = __shfl_up(v, o, 64);
    if (lane >= o) v += t;
  }
  if (lane < SCAN_BLOCKS) bsum[lane] = v - orig;  // exclusive
}

__global__ __launch_bounds__(1024) void k_scan3(int* __restrict__ off, int* __restrict__ ofs,
                                                const int* __restrict__ bsum) {
  int i = blockIdx.x * 1024 + threadIdx.x;
  if (i < N_NODES) {
    int v = off[i] + bsum[blockIdx.x];
    off[i] = v;
    ofs[i] = v;
  }
  if (i == 0) off[N_NODES] = N_EDGES;
}

__global__ __launch_bounds__(256) void k_scatter(const int* __restrict__ ei, int* __restrict__ ofs,
                                                 int* __restrict__ esrc) {
  int e = blockIdx.x * 256 + threadIdx.x;
  if (e < N_EDGES) {
    int d = ei[N_EDGES + e];
    int p = atomicAdd(&ofs[d], 1);
    esrc[p] = ei[e];
  }
}

// ---------------- Layer 0 node linear: h0 = [x | emb] @ W0, plus alpha_s/alpha_d ----------------
// one block of 128 threads per node; thread j computes output channel j (j = head*64 + c)

__global__ __launch_bounds__(128) void k_node0(const float* __restrict__ x,
                                               const float* __restrict__ emb,
                                               const float* __restrict__ W0,
                                               const float* __restrict__ asrc,
                                               const float* __restrict__ adst,
                                               float* __restrict__ h0, float* __restrict__ as0,
                                               float* __restrict__ ad0) {
  int n = blockIdx.x;
  int tid = threadIdx.x;
  __shared__ float hin[D_IN];
  if (tid < F_IN) {
    hin[tid] = x[n * X_STRIDE + tid];
  } else if (tid < D_IN) {
    int cid = (int)x[n * X_STRIDE + F_IN];
    cid = cid < 0 ? 0 : (cid >= NUM_CELLS ? NUM_CELLS - 1 : cid);  // fault guard
    hin[tid] = emb[cid * CELL_DIM + (tid - F_IN)];
  }
  __syncthreads();
  float acc = 0.f;
#pragma unroll
  for (int k = 0; k < D_IN; ++k) acc += hin[k] * W0[k * 128 + tid];
  h0[n * 128 + tid] = acc;
  int head = tid >> 6, lane = tid & 63;
  float sa = acc * asrc[head * 64 + lane];
  float sd = acc * adst[head * 64 + lane];
#pragma unroll
  for (int o = 32; o >= 1; o >>= 1) {
    sa += __shfl_xor(sa, o, 64);
    sd += __shfl_xor(sd, o, 64);
  }
  if (lane == 0) {
    as0[n * 2 + head] = sa;
    ad0[n * 2 + head] = sd;
  }
}

// ---------------- Fused: GAT-aggregate layer0 + mean-heads + bias + LayerNorm + ELU + linear1 + alpha1 ----------------
// one wave per destination node; lane l owns channel l of both heads

__global__ __launch_bounds__(256) void k_agg0(const int* __restrict__ off, const int* __restrict__ esrc,
                                              const float* __restrict__ h0, const float* __restrict__ as0,
                                              const float* __restrict__ ad0,
                                              const float* __restrict__ b0,
                                              const float* __restrict__ lng,
                                              const float* __restrict__ lnb,
                                              const float* __restrict__ W1,
                                              const float* __restrict__ asrc1,
                                              const float* __restrict__ adst1,
                                              float* __restrict__ h1f, float* __restrict__ as1,
                                              float* __restrict__ ad1) {
  int n = blockIdx.x * 4 + (threadIdx.x >> 6);
  int lane = threadIdx.x & 63;
  float adh0 = ad0[2 * n], adh1 = ad0[2 * n + 1];
  float acc0 = 0.f, acc1 = 0.f, den0 = 0.f, den1 = 0.f;
  int i0 = off[n], i1 = off[n + 1];
  for (int i = i0; i < i1; ++i) {
    int s = esrc[i];
    float e0 = as0[2 * s] + adh0;
    e0 = e0 > 0.f ? e0 : NEG_SLOPE * e0;
    float e1 = as0[2 * s + 1] + adh1;
    e1 = e1 > 0.f ? e1 : NEG_SLOPE * e1;
    float w0 = __expf(e0), w1 = __expf(e1);
    const float* hp = h0 + s * 128;
    acc0 += w0 * hp[lane];
    acc1 += w1 * hp[64 + lane];
    den0 += w0;
    den1 += w1;
  }
  {  // appended self-loop edge (n -> n)
    float e0 = as0[2 * n] + adh0;
    e0 = e0 > 0.f ? e0 : NEG_SLOPE * e0;
    float e1 = as0[2 * n + 1] + adh1;
    e1 = e1 > 0.f ? e1 : NEG_SLOPE * e1;
    float w0 = __expf(e0), w1 = __expf(e1);
    const float* hp = h0 + n * 128;
    acc0 += w0 * hp[lane];
    acc1 += w1 * hp[64 + lane];
    den0 += w0;
    den1 += w1;
  }
  float v = 0.5f * (acc0 / den0 + acc1 / den1) + b0[lane];
  // LayerNorm across the 64 channels (one wave)
  float mu = v;
#pragma unroll
  for (int o = 32; o >= 1; o >>= 1) mu += __shfl_xor(mu, o, 64);
  mu *= (1.0f / 64.0f);
  float d = v - mu;
  float vr = d * d;
#pragma unroll
  for (int o = 32; o >= 1; o >>= 1) vr += __shfl_xor(vr, o, 64);
  vr *= (1.0f / 64.0f);
  float y = d * rsqrtf(vr + 1e-5f) * lng[lane] + lnb[lane];
  // ELU
  y = y > 0.f ? y : expm1f(y);
  // linear1: h1[c] = sum_k y_k * W1[k,c]; broadcast y_k via shfl
  float h1v = 0.f;
#pragma unroll
  for (int k = 0; k < 64; ++k) {
    float yk = __shfl(y, k, 64);
    h1v += yk * W1[k * 64 + lane];
  }
  h1f[n * 64 + lane] = h1v;
  float sa = h1v * asrc1[lane];
  float sd = h1v * adst1[lane];
#pragma unroll
  for (int o = 32; o >= 1; o >>= 1) {
    sa += __shfl_xor(sa, o, 64);
    sd += __shfl_xor(sd, o, 64);
  }
  if (lane == 0) {
    as1[n] = sa;
    ad1[n] = sd;
  }
}

// ---------------- Layer 1 aggregate -> output ----------------

__global__ __launch_bounds__(256) void k_agg1(const int* __restrict__ off, const int* __restrict__ esrc,
                                              const float* __restrict__ h1f, const float* __restrict__ as1,
                                              const float* __restrict__ ad1,
                                              const float* __restrict__ b1,
                                              float* __restrict__ out) {
  int n = blockIdx.x * 4 + (threadIdx.x >> 6);
  int lane = threadIdx.x & 63;
  float adv = ad1[n];
  float acc = 0.f, den = 0.f;
  int i0 = off[n], i1 = off[n + 1];
  for (int i = i0; i < i1; ++i) {
    int s = esrc[i];
    float e = as1[s] + adv;
    e = e > 0.f ? e : NEG_SLOPE * e;
    float w = __expf(e);
    acc += w * h1f[s * 64 + lane];
    den += w;
  }
  {  // self loop
    float e = as1[n] + adv;
    e = e > 0.f ? e : NEG_SLOPE * e;
    float w = __expf(e);
    acc += w * h1f[n * 64 + lane];
    den += w;
  }
  out[n * 64 + lane] = acc / den + b1[lane];
}

// ---------------- host ----------------

extern "C" void kernel_launch(void* const* d_in, const int* in_sizes, int n_in,
                              void* d_out, int out_size, void* d_ws, size_t ws_size,
                              hipStream_t stream) {
  const float* x    = (const float*)d_in[0];
  const int*   ei   = (const int*)d_in[1];
  const float* emb  = (const float*)d_in[2];
  const float* W0   = (const float*)d_in[3];
  const float* as0w = (const float*)d_in[4];
  const float* ad0w = (const float*)d_in[5];
  const float* b0   = (const float*)d_in[6];
  const float* lng  = (const float*)d_in[7];
  const float* lnb  = (const float*)d_in[8];
  const float* W1   = (const float*)d_in[9];
  const float* as1w = (const float*)d_in[10];
  const float* ad1w = (const float*)d_in[11];
  const float* b1   = (const float*)d_in[12];
  float* out = (float*)d_out;

  // workspace layout (all 4B-aligned); total ~43.6 MB
  float* h0  = (float*)d_ws;            // N*128
  float* as0 = h0 + N_NODES * 128;      // N*2
  float* ad0 = as0 + N_NODES * 2;       // N*2
  float* h1f = ad0 + N_NODES * 2;       // N*64
  float* as1 = h1f + N_NODES * 64;      // N
  float* ad1 = as1 + N_NODES;           // N
  int* deg  = (int*)(ad1 + N_NODES);    // N
  int* off  = deg + N_NODES;            // N+1
  int* ofs  = off + N_NODES + 1;        // N
  int* bsum = ofs + N_NODES;            // 64
  int* esrc = bsum + 64;                // E

  hipMemsetAsync(deg, 0, N_NODES * sizeof(int), stream);
  k_hist<<<(N_EDGES + 255) / 256, 256, 0, stream>>>(ei, deg);
  k_scan1<<<SCAN_BLOCKS, 1024, 0, stream>>>(deg, off, bsum);
  k_scan2<<<1, 64, 0, stream>>>(bsum);
  k_scan3<<<SCAN_BLOCKS, 1024, 0, stream>>>(off, ofs, bsum);
  k_scatter<<<(N_EDGES + 255) / 256, 256, 0, stream>>>(ei, ofs, esrc);
  k_node0<<<N_NODES, 128, 0, stream>>>(x, emb, W0, as0w, ad0w, h0, as0, ad0);
  k_agg0<<<N_NODES / 4, 256, 0, stream>>>(off, esrc, h0, as0, ad0, b0, lng, lnb, W1, as1w, ad1w,
                                          h1f, as1, ad1);
  k_agg1<<<N_NODES / 4, 256, 0, stream>>>(off, esrc, h1f, as1, ad1, b1, out);
}

// Round 3
// 344.578 us; speedup vs baseline: 1.1749x; 1.1749x over previous
//
#include <hip/hip_runtime.h>
#include <hip/hip_bf16.h>

#define N_NODES 50000
#define N_EDGES 800000
#define F_IN 32
#define CELL_DIM 16
#define D_IN 48      // F_IN + CELL_DIM
#define C_DIM 64
#define X_STRIDE 33  // F_IN + 1 (cell id column)
#define NUM_CELLS 854
#define NEG_SLOPE 0.2f
#define SCAN_BLOCKS 49  // ceil(50000/1024)

// f32 -> bf16 bits, round-to-nearest-even
static __device__ __forceinline__ unsigned f2b(float f) {
  unsigned x = __float_as_uint(f);
  return (x + 0x7fffu + ((x >> 16) & 1u)) >> 16;
}
// low/high bf16 halves of a packed word -> f32
static __device__ __forceinline__ float b2f_lo(unsigned w) { return __uint_as_float(w << 16); }
static __device__ __forceinline__ float b2f_hi(unsigned w) { return __uint_as_float(w & 0xffff0000u); }

// ---------------- CSR build ----------------

__global__ __launch_bounds__(256) void k_hist(const int* __restrict__ ei, int* __restrict__ deg) {
  int e = blockIdx.x * 256 + threadIdx.x;
  if (e < N_EDGES) atomicAdd(&deg[ei[N_EDGES + e]], 1);
}

// shfl-based scan: wave-inclusive scan + 16 wave sums scanned by wave 0; 2 barriers
__global__ __launch_bounds__(1024) void k_scan1(const int* __restrict__ deg, int* __restrict__ off,
                                                int* __restrict__ bsum) {
  __shared__ int ws[16];
  int tid = threadIdx.x;
  int lane = tid & 63, wid = tid >> 6;
  int i = blockIdx.x * 1024 + tid;
  int v = (i < N_NODES) ? deg[i] : 0;
  int sc = v;
#pragma unroll
  for (int o = 1; o < 64; o <<= 1) {
    int t = __shfl_up(sc, o, 64);
    if (lane >= o) sc += t;
  }
  if (lane == 63) ws[wid] = sc;
  __syncthreads();
  if (tid < 16) {
    int w = ws[tid];
    int s = w;
#pragma unroll
    for (int o = 1; o < 16; o <<= 1) {
      int t = __shfl_up(s, o, 64);
      if (tid >= o) s += t;
    }
    ws[tid] = s - w;  // exclusive wave prefix
  }
  __syncthreads();
  int excl = sc - v + ws[wid];
  if (i < N_NODES) off[i] = excl;
  if (tid == 1023) bsum[blockIdx.x] = excl + v;
}

__global__ __launch_bounds__(64) void k_scan2(int* __restrict__ bsum) {
  int lane = threadIdx.x;
  int v = (lane < SCAN_BLOCKS) ? bsum[lane] : 0;
  int orig = v;
  for (int o = 1; o < 64; o <<= 1) {
    int t = __shfl_up(v, o, 64);
    if (lane >= o) v += t;
  }
  if (lane < SCAN_BLOCKS) bsum[lane] = v - orig;  // exclusive
}

__global__ __launch_bounds__(1024) void k_scan3(int* __restrict__ off, int* __restrict__ ofs,
                                                const int* __restrict__ bsum) {
  int i = blockIdx.x * 1024 + threadIdx.x;
  if (i < N_NODES) {
    int v = off[i] + bsum[blockIdx.x];
    off[i] = v;
    ofs[i] = v;
  }
  if (i == 0) off[N_NODES] = N_EDGES;
}

__global__ __launch_bounds__(256) void k_scatter(const int* __restrict__ ei, int* __restrict__ ofs,
                                                 int* __restrict__ esrc) {
  int e = blockIdx.x * 256 + threadIdx.x;
  if (e < N_EDGES) {
    int d = ei[N_EDGES + e];
    int p = atomicAdd(&ofs[d], 1);
    esrc[p] = ei[e];
  }
}

// ---------------- Layer 0 node linear: h0 = [x | emb] @ W0, packed bf16x2 (head0,head1)/channel ----

__global__ __launch_bounds__(128) void k_node0(const float* __restrict__ x,
                                               const float* __restrict__ emb,
                                               const float* __restrict__ W0,
                                               const float* __restrict__ asrc,
                                               const float* __restrict__ adst,
                                               unsigned* __restrict__ h0p, float* __restrict__ as0,
                                               float* __restrict__ ad0) {
  int n = blockIdx.x;
  int tid = threadIdx.x;
  __shared__ float hin[D_IN];
  __shared__ float sh[128];
  if (tid < F_IN) {
    hin[tid] = x[n * X_STRIDE + tid];
  } else if (tid < D_IN) {
    int cid = (int)x[n * X_STRIDE + F_IN];
    cid = cid < 0 ? 0 : (cid >= NUM_CELLS ? NUM_CELLS - 1 : cid);  // fault guard
    hin[tid] = emb[cid * CELL_DIM + (tid - F_IN)];
  }
  __syncthreads();
  float acc = 0.f;
#pragma unroll
  for (int k = 0; k < D_IN; ++k) acc += hin[k] * W0[k * 128 + tid];
  sh[tid] = acc;
  int head = tid >> 6, lane = tid & 63;
  float sa = acc * asrc[head * 64 + lane];
  float sd = acc * adst[head * 64 + lane];
#pragma unroll
  for (int o = 32; o >= 1; o >>= 1) {
    sa += __shfl_xor(sa, o, 64);
    sd += __shfl_xor(sd, o, 64);
  }
  if (lane == 0) {
    as0[n * 2 + head] = sa;
    ad0[n * 2 + head] = sd;
  }
  __syncthreads();
  if (tid < 64) h0p[n * 64 + tid] = f2b(sh[tid]) | (f2b(sh[64 + tid]) << 16);
}

// ---------------- Fused: aggregate L0 + mean-heads + bias + LN + ELU + linear1 + alpha1 ----------------
// one wave per destination node; lane l owns channel l of both heads

__global__ __launch_bounds__(256) void k_agg0(const int* __restrict__ off, const int* __restrict__ esrc,
                                              const unsigned* __restrict__ h0p,
                                              const float2* __restrict__ as0v,
                                              const float2* __restrict__ ad0v,
                                              const float* __restrict__ b0,
                                              const float* __restrict__ lng,
                                              const float* __restrict__ lnb,
                                              const float* __restrict__ W1,
                                              const float* __restrict__ asrc1,
                                              const float* __restrict__ adst1,
                                              unsigned short* __restrict__ h1b,
                                              float* __restrict__ as1, float* __restrict__ ad1) {
  int n = blockIdx.x * 4 + (threadIdx.x >> 6);
  int lane = threadIdx.x & 63;
  float2 adh = ad0v[n];
  float acc0 = 0.f, acc1 = 0.f, den0 = 0.f, den1 = 0.f;
  int i0 = off[n], i1 = off[n + 1];
  int i = i0;
  for (; i + 1 < i1; i += 2) {
    int sA = esrc[i], sB = esrc[i + 1];
    float2 aA = as0v[sA];
    float2 aB = as0v[sB];
    unsigned wA = h0p[sA * 64 + lane];
    unsigned wB = h0p[sB * 64 + lane];
    float e0 = aA.x + adh.x; e0 = e0 > 0.f ? e0 : NEG_SLOPE * e0;
    float e1 = aA.y + adh.y; e1 = e1 > 0.f ? e1 : NEG_SLOPE * e1;
    float w0 = __expf(e0), w1 = __expf(e1);
    acc0 += w0 * b2f_lo(wA); acc1 += w1 * b2f_hi(wA);
    den0 += w0; den1 += w1;
    e0 = aB.x + adh.x; e0 = e0 > 0.f ? e0 : NEG_SLOPE * e0;
    e1 = aB.y + adh.y; e1 = e1 > 0.f ? e1 : NEG_SLOPE * e1;
    w0 = __expf(e0); w1 = __expf(e1);
    acc0 += w0 * b2f_lo(wB); acc1 += w1 * b2f_hi(wB);
    den0 += w0; den1 += w1;
  }
  for (; i < i1; ++i) {
    int s = esrc[i];
    float2 a = as0v[s];
    unsigned w = h0p[s * 64 + lane];
    float e0 = a.x + adh.x; e0 = e0 > 0.f ? e0 : NEG_SLOPE * e0;
    float e1 = a.y + adh.y; e1 = e1 > 0.f ? e1 : NEG_SLOPE * e1;
    float w0 = __expf(e0), w1 = __expf(e1);
    acc0 += w0 * b2f_lo(w); acc1 += w1 * b2f_hi(w);
    den0 += w0; den1 += w1;
  }
  {  // appended self-loop edge (n -> n)
    float2 a = as0v[n];
    unsigned w = h0p[n * 64 + lane];
    float e0 = a.x + adh.x; e0 = e0 > 0.f ? e0 : NEG_SLOPE * e0;
    float e1 = a.y + adh.y; e1 = e1 > 0.f ? e1 : NEG_SLOPE * e1;
    float w0 = __expf(e0), w1 = __expf(e1);
    acc0 += w0 * b2f_lo(w); acc1 += w1 * b2f_hi(w);
    den0 += w0; den1 += w1;
  }
  float v = 0.5f * (acc0 / den0 + acc1 / den1) + b0[lane];
  // LayerNorm across the 64 channels (one wave)
  float mu = v;
#pragma unroll
  for (int o = 32; o >= 1; o >>= 1) mu += __shfl_xor(mu, o, 64);
  mu *= (1.0f / 64.0f);
  float d = v - mu;
  float vr = d * d;
#pragma unroll
  for (int o = 32; o >= 1; o >>= 1) vr += __shfl_xor(vr, o, 64);
  vr *= (1.0f / 64.0f);
  float y = d * rsqrtf(vr + 1e-5f) * lng[lane] + lnb[lane];
  // ELU
  y = y > 0.f ? y : expm1f(y);
  // linear1: h1[c] = sum_k y_k * W1[k,c]
  float h1v = 0.f;
#pragma unroll
  for (int k = 0; k < 64; ++k) {
    float yk = __shfl(y, k, 64);
    h1v += yk * W1[k * 64 + lane];
  }
  h1b[n * 64 + lane] = (unsigned short)f2b(h1v);
  float sa = h1v * asrc1[lane];
  float sd = h1v * adst1[lane];
#pragma unroll
  for (int o = 32; o >= 1; o >>= 1) {
    sa += __shfl_xor(sa, o, 64);
    sd += __shfl_xor(sd, o, 64);
  }
  if (lane == 0) {
    as1[n] = sa;
    ad1[n] = sd;
  }
}

// ---------------- Layer 1 aggregate -> output ----------------

__global__ __launch_bounds__(256) void k_agg1(const int* __restrict__ off, const int* __restrict__ esrc,
                                              const unsigned short* __restrict__ h1b,
                                              const float* __restrict__ as1,
                                              const float* __restrict__ ad1,
                                              const float* __restrict__ b1,
                                              float* __restrict__ out) {
  int n = blockIdx.x * 4 + (threadIdx.x >> 6);
  int lane = threadIdx.x & 63;
  float adv = ad1[n];
  float acc = 0.f, den = 0.f;
  int i0 = off[n], i1 = off[n + 1];
  int i = i0;
  for (; i + 1 < i1; i += 2) {
    int sA = esrc[i], sB = esrc[i + 1];
    float aA = as1[sA], aB = as1[sB];
    unsigned hA = h1b[sA * 64 + lane];
    unsigned hB = h1b[sB * 64 + lane];
    float e = aA + adv; e = e > 0.f ? e : NEG_SLOPE * e;
    float w = __expf(e);
    acc += w * __uint_as_float(hA << 16); den += w;
    e = aB + adv; e = e > 0.f ? e : NEG_SLOPE * e;
    w = __expf(e);
    acc += w * __uint_as_float(hB << 16); den += w;
  }
  for (; i < i1; ++i) {
    int s = esrc[i];
    float e = as1[s] + adv;
    e = e > 0.f ? e : NEG_SLOPE * e;
    float w = __expf(e);
    acc += w * __uint_as_float((unsigned)h1b[s * 64 + lane] << 16);
    den += w;
  }
  {  // self loop
    float e = as1[n] + adv;
    e = e > 0.f ? e : NEG_SLOPE * e;
    float w = __expf(e);
    acc += w * __uint_as_float((unsigned)h1b[n * 64 + lane] << 16);
    den += w;
  }
  out[n * 64 + lane] = acc / den + b1[lane];
}

// ---------------- host ----------------

extern "C" void kernel_launch(void* const* d_in, const int* in_sizes, int n_in,
                              void* d_out, int out_size, void* d_ws, size_t ws_size,
                              hipStream_t stream) {
  const float* x    = (const float*)d_in[0];
  const int*   ei   = (const int*)d_in[1];
  const float* emb  = (const float*)d_in[2];
  const float* W0   = (const float*)d_in[3];
  const float* as0w = (const float*)d_in[4];
  const float* ad0w = (const float*)d_in[5];
  const float* b0   = (const float*)d_in[6];
  const float* lng  = (const float*)d_in[7];
  const float* lnb  = (const float*)d_in[8];
  const float* W1   = (const float*)d_in[9];
  const float* as1w = (const float*)d_in[10];
  const float* ad1w = (const float*)d_in[11];
  const float* b1   = (const float*)d_in[12];
  float* out = (float*)d_out;

  // workspace layout
  float* as0 = (float*)d_ws;                 // N*2
  float* ad0 = as0 + N_NODES * 2;            // N*2
  float* as1 = ad0 + N_NODES * 2;            // N
  float* ad1 = as1 + N_NODES;                // N
  unsigned* h0p = (unsigned*)(ad1 + N_NODES);       // N*64 (bf16x2 packed)
  unsigned short* h1b = (unsigned short*)(h0p + N_NODES * 64);  // N*64 bf16
  int* deg  = (int*)(h1b + N_NODES * 64);    // N
  int* off  = deg + N_NODES;                 // N+1
  int* ofs  = off + N_NODES + 1;             // N
  int* bsum = ofs + N_NODES;                 // 64
  int* esrc = bsum + 64;                     // E

  hipMemsetAsync(deg, 0, N_NODES * sizeof(int), stream);
  k_hist<<<(N_EDGES + 255) / 256, 256, 0, stream>>>(ei, deg);
  k_scan1<<<SCAN_BLOCKS, 1024, 0, stream>>>(deg, off, bsum);
  k_scan2<<<1, 64, 0, stream>>>(bsum);
  k_scan3<<<SCAN_BLOCKS, 1024, 0, stream>>>(off, ofs, bsum);
  k_scatter<<<(N_EDGES + 255) / 256, 256, 0, stream>>>(ei, ofs, esrc);
  k_node0<<<N_NODES, 128, 0, stream>>>(x, emb, W0, as0w, ad0w, h0p, as0, ad0);
  k_agg0<<<N_NODES / 4, 256, 0, stream>>>(off, esrc, h0p, (const float2*)as0, (const float2*)ad0,
                                          b0, lng, lnb, W1, as1w, ad1w, h1b, as1, ad1);
  k_agg1<<<N_NODES / 4, 256, 0, stream>>>(off, esrc, h1b, as1, ad1, b1, out);
}

// Round 4
// 320.414 us; speedup vs baseline: 1.2635x; 1.0754x over previous
//
#include <hip/hip_runtime.h>
#include <hip/hip_bf16.h>

#define N_NODES 50000
#define N_EDGES 800000
#define E_TOT 850000  // edges + self loops, CSR-resident
#define F_IN 32
#define CELL_DIM 16
#define D_IN 48      // F_IN + CELL_DIM
#define X_STRIDE 33  // F_IN + 1 (cell id column)
#define NUM_CELLS 854
#define NEG_SLOPE 0.2f
#define SCAN_BLOCKS 49  // ceil(50000/1024)

typedef unsigned int uint;
typedef unsigned short ushort;

// f32 -> bf16 bits, round-to-nearest-even
static __device__ __forceinline__ uint f2b(float f) {
  uint x = __float_as_uint(f);
  return (x + 0x7fffu + ((x >> 16) & 1u)) >> 16;
}
static __device__ __forceinline__ float b2f_lo(uint w) { return __uint_as_float(w << 16); }
static __device__ __forceinline__ float b2f_hi(uint w) { return __uint_as_float(w & 0xffff0000u); }
static __device__ __forceinline__ float lrelu(float e) { return e > 0.f ? e : NEG_SLOPE * e; }

// ---------------- CSR build ----------------

__global__ __launch_bounds__(256) void k_hist(const int* __restrict__ ei, int* __restrict__ deg) {
  int e = blockIdx.x * 256 + threadIdx.x;
  if (e < N_EDGES) atomicAdd(&deg[ei[N_EDGES + e]], 1);
}

// shfl-based block scan of (deg+1); 2 barriers
__global__ __launch_bounds__(1024) void k_scan1(const int* __restrict__ deg, int* __restrict__ off,
                                                int* __restrict__ bsum) {
  __shared__ int ws[16];
  int tid = threadIdx.x;
  int lane = tid & 63, wid = tid >> 6;
  int i = blockIdx.x * 1024 + tid;
  int v = (i < N_NODES) ? deg[i] + 1 : 0;  // +1 slot for self-loop
  int sc = v;
#pragma unroll
  for (int o = 1; o < 64; o <<= 1) {
    int t = __shfl_up(sc, o, 64);
    if (lane >= o) sc += t;
  }
  if (lane == 63) ws[wid] = sc;
  __syncthreads();
  if (tid < 16) {
    int w = ws[tid];
    int s = w;
#pragma unroll
    for (int o = 1; o < 16; o <<= 1) {
      int t = __shfl_up(s, o, 64);
      if (tid >= o) s += t;
    }
    ws[tid] = s - w;  // exclusive wave prefix
  }
  __syncthreads();
  int excl = sc - v + ws[wid];
  if (i < N_NODES) off[i] = excl;
  if (tid == 1023) bsum[blockIdx.x] = excl + v;
}

__global__ __launch_bounds__(64) void k_scan2(int* __restrict__ bsum) {
  int lane = threadIdx.x;
  int v = (lane < SCAN_BLOCKS) ? bsum[lane] : 0;
  int orig = v;
  for (int o = 1; o < 64; o <<= 1) {
    int t = __shfl_up(v, o, 64);
    if (lane >= o) v += t;
  }
  if (lane < SCAN_BLOCKS) bsum[lane] = v - orig;  // exclusive
}

__global__ __launch_bounds__(1024) void k_scan3(int* __restrict__ off, int* __restrict__ ofs,
                                                const int* __restrict__ bsum) {
  int i = blockIdx.x * 1024 + threadIdx.x;
  if (i < N_NODES) {
    int v = off[i] + bsum[blockIdx.x];
    off[i] = v;
    ofs[i] = v;
  }
  if (i == 0) off[N_NODES] = E_TOT;
}

// scatter edges into CSR slots AND compute layer-0 attention weights (edge-parallel)
__global__ __launch_bounds__(256) void k_scatter(const int* __restrict__ ei, int* __restrict__ ofs,
                                                 const float2* __restrict__ as0v,
                                                 const float2* __restrict__ ad0v,
                                                 uint2* __restrict__ ew, int2* __restrict__ sd) {
  int e = blockIdx.x * 256 + threadIdx.x;
  if (e < N_EDGES) {
    int s = ei[e], d = ei[N_EDGES + e];
    float2 a_s = as0v[s], a_d = ad0v[d];
    float w0 = __expf(lrelu(a_s.x + a_d.x));
    float w1 = __expf(lrelu(a_s.y + a_d.y));
    int p = atomicAdd(&ofs[d], 1);
    ew[p] = make_uint2((uint)s, f2b(w0) | (f2b(w1) << 16));
    sd[p] = make_int2(s, d);
  }
}

// fill the reserved last slot of each node with its self-loop record
__global__ __launch_bounds__(256) void k_self(const int* __restrict__ off,
                                              const float2* __restrict__ as0v,
                                              const float2* __restrict__ ad0v,
                                              uint2* __restrict__ ew, int2* __restrict__ sd) {
  int n = blockIdx.x * 256 + threadIdx.x;
  if (n < N_NODES) {
    int slot = off[n + 1] - 1;
    float2 a_s = as0v[n], a_d = ad0v[n];
    float w0 = __expf(lrelu(a_s.x + a_d.x));
    float w1 = __expf(lrelu(a_s.y + a_d.y));
    ew[slot] = make_uint2((uint)n, f2b(w0) | (f2b(w1) << 16));
    sd[slot] = make_int2(n, n);
  }
}

// ---------------- Layer 0 node linear: h0 = [x | emb] @ W0, packed bf16x2 (head0,head1)/channel ----

__global__ __launch_bounds__(128) void k_node0(const float* __restrict__ x,
                                               const float* __restrict__ emb,
                                               const float* __restrict__ W0,
                                               const float* __restrict__ asrc,
                                               const float* __restrict__ adst,
                                               uint* __restrict__ h0p, float* __restrict__ as0,
                                               float* __restrict__ ad0) {
  int n = blockIdx.x;
  int tid = threadIdx.x;
  __shared__ float hin[D_IN];
  __shared__ float sh[128];
  if (tid < F_IN) {
    hin[tid] = x[n * X_STRIDE + tid];
  } else if (tid < D_IN) {
    int cid = (int)x[n * X_STRIDE + F_IN];
    cid = cid < 0 ? 0 : (cid >= NUM_CELLS ? NUM_CELLS - 1 : cid);  // fault guard
    hin[tid] = emb[cid * CELL_DIM + (tid - F_IN)];
  }
  __syncthreads();
  float acc = 0.f;
#pragma unroll
  for (int k = 0; k < D_IN; ++k) acc += hin[k] * W0[k * 128 + tid];
  sh[tid] = acc;
  int head = tid >> 6, lane = tid & 63;
  float sa = acc * asrc[head * 64 + lane];
  float sd = acc * adst[head * 64 + lane];
#pragma unroll
  for (int o = 32; o >= 1; o >>= 1) {
    sa += __shfl_xor(sa, o, 64);
    sd += __shfl_xor(sd, o, 64);
  }
  if (lane == 0) {
    as0[n * 2 + head] = sa;
    ad0[n * 2 + head] = sd;
  }
  __syncthreads();
  if (tid < 64) h0p[n * 64 + tid] = f2b(sh[tid]) | (f2b(sh[64 + tid]) << 16);
}

// ---------------- Fused: aggregate L0 + mean-heads + bias + LN + ELU + linear1 + alpha1 ----------------
// one wave per destination node; lane l owns channel l of both heads; weights precomputed

__global__ __launch_bounds__(256) void k_agg0(const int* __restrict__ off,
                                              const uint2* __restrict__ ew,
                                              const uint* __restrict__ h0p,
                                              const float* __restrict__ b0,
                                              const float* __restrict__ lng,
                                              const float* __restrict__ lnb,
                                              const float* __restrict__ W1,
                                              const float* __restrict__ asrc1,
                                              const float* __restrict__ adst1,
                                              ushort* __restrict__ h1b,
                                              float* __restrict__ as1, float* __restrict__ ad1) {
  int n = blockIdx.x * 4 + (threadIdx.x >> 6);
  int lane = threadIdx.x & 63;
  float acc0 = 0.f, acc1 = 0.f, den0 = 0.f, den1 = 0.f;
  int i0 = off[n], i1 = off[n + 1];
  int i = i0;
  for (; i + 3 < i1; i += 4) {
    uint2 rA = ew[i], rB = ew[i + 1], rC = ew[i + 2], rD = ew[i + 3];
    uint hA = h0p[rA.x * 64 + lane];
    uint hB = h0p[rB.x * 64 + lane];
    uint hC = h0p[rC.x * 64 + lane];
    uint hD = h0p[rD.x * 64 + lane];
    float w;
    w = b2f_lo(rA.y); acc0 += w * b2f_lo(hA); den0 += w;
    w = b2f_hi(rA.y); acc1 += w * b2f_hi(hA); den1 += w;
    w = b2f_lo(rB.y); acc0 += w * b2f_lo(hB); den0 += w;
    w = b2f_hi(rB.y); acc1 += w * b2f_hi(hB); den1 += w;
    w = b2f_lo(rC.y); acc0 += w * b2f_lo(hC); den0 += w;
    w = b2f_hi(rC.y); acc1 += w * b2f_hi(hC); den1 += w;
    w = b2f_lo(rD.y); acc0 += w * b2f_lo(hD); den0 += w;
    w = b2f_hi(rD.y); acc1 += w * b2f_hi(hD); den1 += w;
  }
  for (; i < i1; ++i) {
    uint2 r = ew[i];
    uint h = h0p[r.x * 64 + lane];
    float w;
    w = b2f_lo(r.y); acc0 += w * b2f_lo(h); den0 += w;
    w = b2f_hi(r.y); acc1 += w * b2f_hi(h); den1 += w;
  }
  float v = 0.5f * (acc0 / den0 + acc1 / den1) + b0[lane];
  // LayerNorm across the 64 channels (one wave)
  float mu = v;
#pragma unroll
  for (int o = 32; o >= 1; o >>= 1) mu += __shfl_xor(mu, o, 64);
  mu *= (1.0f / 64.0f);
  float d = v - mu;
  float vr = d * d;
#pragma unroll
  for (int o = 32; o >= 1; o >>= 1) vr += __shfl_xor(vr, o, 64);
  vr *= (1.0f / 64.0f);
  float y = d * rsqrtf(vr + 1e-5f) * lng[lane] + lnb[lane];
  // ELU
  y = y > 0.f ? y : expm1f(y);
  // linear1: h1[c] = sum_k y_k * W1[k,c]
  float h1v = 0.f;
#pragma unroll
  for (int k = 0; k < 64; ++k) {
    float yk = __shfl(y, k, 64);
    h1v += yk * W1[k * 64 + lane];
  }
  h1b[n * 64 + lane] = (ushort)f2b(h1v);
  float sa = h1v * asrc1[lane];
  float sdv = h1v * adst1[lane];
#pragma unroll
  for (int o = 32; o >= 1; o >>= 1) {
    sa += __shfl_xor(sa, o, 64);
    sdv += __shfl_xor(sdv, o, 64);
  }
  if (lane == 0) {
    as1[n] = sa;
    ad1[n] = sdv;
  }
}

// ---------------- Layer-1 edge weights (edge-parallel) ----------------

__global__ __launch_bounds__(256) void k_w1(const int2* __restrict__ sd,
                                            const float* __restrict__ as1,
                                            const float* __restrict__ ad1,
                                            uint2* __restrict__ ew1) {
  int i = blockIdx.x * 256 + threadIdx.x;
  if (i < E_TOT) {
    int2 p = sd[i];
    float w = __expf(lrelu(as1[p.x] + ad1[p.y]));
    ew1[i] = make_uint2((uint)p.x, __float_as_uint(w));
  }
}

// ---------------- Layer 1 aggregate -> output ----------------

__global__ __launch_bounds__(256) void k_agg1(const int* __restrict__ off,
                                              const uint2* __restrict__ ew1,
                                              const ushort* __restrict__ h1b,
                                              const float* __restrict__ b1,
                                              float* __restrict__ out) {
  int n = blockIdx.x * 4 + (threadIdx.x >> 6);
  int lane = threadIdx.x & 63;
  float acc = 0.f, den = 0.f;
  int i0 = off[n], i1 = off[n + 1];
  int i = i0;
  for (; i + 3 < i1; i += 4) {
    uint2 rA = ew1[i], rB = ew1[i + 1], rC = ew1[i + 2], rD = ew1[i + 3];
    uint hA = h1b[rA.x * 64 + lane];
    uint hB = h1b[rB.x * 64 + lane];
    uint hC = h1b[rC.x * 64 + lane];
    uint hD = h1b[rD.x * 64 + lane];
    float w;
    w = __uint_as_float(rA.y); acc += w * __uint_as_float(hA << 16); den += w;
    w = __uint_as_float(rB.y); acc += w * __uint_as_float(hB << 16); den += w;
    w = __uint_as_float(rC.y); acc += w * __uint_as_float(hC << 16); den += w;
    w = __uint_as_float(rD.y); acc += w * __uint_as_float(hD << 16); den += w;
  }
  for (; i < i1; ++i) {
    uint2 r = ew1[i];
    uint h = h1b[r.x * 64 + lane];
    float w = __uint_as_float(r.y);
    acc += w * __uint_as_float(h << 16);
    den += w;
  }
  out[n * 64 + lane] = acc / den + b1[lane];
}

// ---------------- host ----------------

extern "C" void kernel_launch(void* const* d_in, const int* in_sizes, int n_in,
                              void* d_out, int out_size, void* d_ws, size_t ws_size,
                              hipStream_t stream) {
  const float* x    = (const float*)d_in[0];
  const int*   ei   = (const int*)d_in[1];
  const float* emb  = (const float*)d_in[2];
  const float* W0   = (const float*)d_in[3];
  const float* as0w = (const float*)d_in[4];
  const float* ad0w = (const float*)d_in[5];
  const float* b0   = (const float*)d_in[6];
  const float* lng  = (const float*)d_in[7];
  const float* lnb  = (const float*)d_in[8];
  const float* W1   = (const float*)d_in[9];
  const float* as1w = (const float*)d_in[10];
  const float* ad1w = (const float*)d_in[11];
  const float* b1   = (const float*)d_in[12];
  float* out = (float*)d_out;

  // workspace layout (8B-aligned arrays first); total ~41.4 MB
  uint2* ew  = (uint2*)d_ws;                  // E_TOT {src, bf16x2 w}
  int2*  sd  = (int2*)(ew + E_TOT);           // E_TOT {src, dst}
  uint2* ew1 = (uint2*)(sd + E_TOT);          // E_TOT {src, f32 w}
  float* as0 = (float*)(ew1 + E_TOT);         // N*2
  float* ad0 = as0 + N_NODES * 2;             // N*2
  float* as1 = ad0 + N_NODES * 2;             // N
  float* ad1 = as1 + N_NODES;                 // N
  uint* h0p = (uint*)(ad1 + N_NODES);         // N*64 (bf16x2 packed)
  ushort* h1b = (ushort*)(h0p + N_NODES * 64);  // N*64 bf16
  int* deg  = (int*)(h1b + N_NODES * 64);     // N
  int* off  = deg + N_NODES;                  // N+1
  int* ofs  = off + N_NODES + 1;              // N
  int* bsum = ofs + N_NODES;                  // 64

  hipMemsetAsync(deg, 0, N_NODES * sizeof(int), stream);
  k_node0<<<N_NODES, 128, 0, stream>>>(x, emb, W0, as0w, ad0w, h0p, as0, ad0);
  k_hist<<<(N_EDGES + 255) / 256, 256, 0, stream>>>(ei, deg);
  k_scan1<<<SCAN_BLOCKS, 1024, 0, stream>>>(deg, off, bsum);
  k_scan2<<<1, 64, 0, stream>>>(bsum);
  k_scan3<<<SCAN_BLOCKS, 1024, 0, stream>>>(off, ofs, bsum);
  k_scatter<<<(N_EDGES + 255) / 256, 256, 0, stream>>>(ei, ofs, (const float2*)as0,
                                                       (const float2*)ad0, ew, sd);
  k_self<<<(N_NODES + 255) / 256, 256, 0, stream>>>(off, (const float2*)as0, (const float2*)ad0,
                                                    ew, sd);
  k_agg0<<<N_NODES / 4, 256, 0, stream>>>(off, ew, h0p, b0, lng, lnb, W1, as1w, ad1w,
                                          h1b, as1, ad1);
  k_w1<<<(E_TOT + 255) / 256, 256, 0, stream>>>(sd, as1, ad1, ew1);
  k_agg1<<<N_NODES / 4, 256, 0, stream>>>(off, ew1, h1b, b1, out);
}

// Round 5
// 318.213 us; speedup vs baseline: 1.2723x; 1.0069x over previous
//
#include <hip/hip_runtime.h>
#include <hip/hip_bf16.h>

#define N_NODES 50000
#define N_EDGES 800000
#define E_TOT 850000  // edges + self loops, CSR-resident
#define F_IN 32
#define CELL_DIM 16
#define D_IN 48      // F_IN + CELL_DIM
#define X_STRIDE 33  // F_IN + 1 (cell id column)
#define NUM_CELLS 854
#define NEG_SLOPE 0.2f
#define SCAN_BLOCKS 49  // ceil(50000/1024)

typedef unsigned int uint;
typedef unsigned short ushort;

// f32 -> bf16 bits, round-to-nearest-even
static __device__ __forceinline__ uint f2b(float f) {
  uint x = __float_as_uint(f);
  return (x + 0x7fffu + ((x >> 16) & 1u)) >> 16;
}
static __device__ __forceinline__ float b2f_lo(uint w) { return __uint_as_float(w << 16); }
static __device__ __forceinline__ float b2f_hi(uint w) { return __uint_as_float(w & 0xffff0000u); }
static __device__ __forceinline__ float lrelu(float e) { return e > 0.f ? e : NEG_SLOPE * e; }

// ---------------- CSR build ----------------

__global__ __launch_bounds__(256) void k_hist(const int* __restrict__ ei, int* __restrict__ deg) {
  int e = blockIdx.x * 256 + threadIdx.x;
  if (e < N_EDGES) atomicAdd(&deg[ei[N_EDGES + e]], 1);
}

// shfl-based block scan of (deg+1); 2 barriers; bsum[b] = block total (unscanned)
__global__ __launch_bounds__(1024) void k_scan1(const int* __restrict__ deg, int* __restrict__ off,
                                                int* __restrict__ bsum) {
  __shared__ int ws[16];
  int tid = threadIdx.x;
  int lane = tid & 63, wid = tid >> 6;
  int i = blockIdx.x * 1024 + tid;
  int v = (i < N_NODES) ? deg[i] + 1 : 0;  // +1 slot for self-loop
  int sc = v;
#pragma unroll
  for (int o = 1; o < 64; o <<= 1) {
    int t = __shfl_up(sc, o, 64);
    if (lane >= o) sc += t;
  }
  if (lane == 63) ws[wid] = sc;
  __syncthreads();
  if (tid < 16) {
    int w = ws[tid];
    int s = w;
#pragma unroll
    for (int o = 1; o < 16; o <<= 1) {
      int t = __shfl_up(s, o, 64);
      if (tid >= o) s += t;
    }
    ws[tid] = s - w;  // exclusive wave prefix
  }
  __syncthreads();
  int excl = sc - v + ws[wid];
  if (i < N_NODES) off[i] = excl;
  if (tid == 1023) bsum[blockIdx.x] = excl + v;  // block total
}

// fused scan2+scan3: each block re-scans the 49 block sums (cheap), adds its prefix
__global__ __launch_bounds__(1024) void k_scan23(int* __restrict__ off, int* __restrict__ ofs,
                                                 const int* __restrict__ bsum) {
  __shared__ int carry_s;
  int tid = threadIdx.x;
  if (tid < 64) {
    int v = (tid < SCAN_BLOCKS) ? bsum[tid] : 0;
    int s = v;
#pragma unroll
    for (int o = 1; o < 64; o <<= 1) {
      int t = __shfl_up(s, o, 64);
      if (tid >= o) s += t;
    }
    if (tid == (int)blockIdx.x) carry_s = s - v;  // exclusive prefix of this block
  }
  __syncthreads();
  int carry = carry_s;
  int i = blockIdx.x * 1024 + tid;
  if (i < N_NODES) {
    int v = off[i] + carry;
    off[i] = v;
    ofs[i] = v;
  }
  if (i == 0) off[N_NODES] = E_TOT;
}

// scatter edges into CSR slots + compute layer-0 attention weights; tail range fills self-loops
__global__ __launch_bounds__(256) void k_scatter(const int* __restrict__ ei, int* __restrict__ ofs,
                                                 const int* __restrict__ off,
                                                 const float2* __restrict__ as0v,
                                                 const float2* __restrict__ ad0v,
                                                 uint2* __restrict__ ew) {
  int t = blockIdx.x * 256 + threadIdx.x;
  if (t < N_EDGES) {
    int s = ei[t], d = ei[N_EDGES + t];
    float2 a_s = as0v[s], a_d = ad0v[d];
    float w0 = __expf(lrelu(a_s.x + a_d.x));
    float w1 = __expf(lrelu(a_s.y + a_d.y));
    int p = atomicAdd(&ofs[d], 1);
    ew[p] = make_uint2((uint)s, f2b(w0) | (f2b(w1) << 16));
  } else if (t < N_EDGES + N_NODES) {
    int n = t - N_EDGES;  // self-loop record in the reserved last slot
    int slot = off[n + 1] - 1;
    float2 a_s = as0v[n], a_d = ad0v[n];
    float w0 = __expf(lrelu(a_s.x + a_d.x));
    float w1 = __expf(lrelu(a_s.y + a_d.y));
    ew[slot] = make_uint2((uint)n, f2b(w0) | (f2b(w1) << 16));
  }
}

// ---------------- Layer 0 node linear: h0 = [x | emb] @ W0, packed bf16x2 (head0,head1)/channel ----

__global__ __launch_bounds__(128) void k_node0(const float* __restrict__ x,
                                               const float* __restrict__ emb,
                                               const float* __restrict__ W0,
                                               const float* __restrict__ asrc,
                                               const float* __restrict__ adst,
                                               uint* __restrict__ h0p, float* __restrict__ as0,
                                               float* __restrict__ ad0) {
  int n = blockIdx.x;
  int tid = threadIdx.x;
  __shared__ float hin[D_IN];
  __shared__ float sh[128];
  if (tid < F_IN) {
    hin[tid] = x[n * X_STRIDE + tid];
  } else if (tid < D_IN) {
    int cid = (int)x[n * X_STRIDE + F_IN];
    cid = cid < 0 ? 0 : (cid >= NUM_CELLS ? NUM_CELLS - 1 : cid);  // fault guard
    hin[tid] = emb[cid * CELL_DIM + (tid - F_IN)];
  }
  __syncthreads();
  float acc = 0.f;
#pragma unroll
  for (int k = 0; k < D_IN; ++k) acc += hin[k] * W0[k * 128 + tid];
  sh[tid] = acc;
  int head = tid >> 6, lane = tid & 63;
  float sa = acc * asrc[head * 64 + lane];
  float sd = acc * adst[head * 64 + lane];
#pragma unroll
  for (int o = 32; o >= 1; o >>= 1) {
    sa += __shfl_xor(sa, o, 64);
    sd += __shfl_xor(sd, o, 64);
  }
  if (lane == 0) {
    as0[n * 2 + head] = sa;
    ad0[n * 2 + head] = sd;
  }
  __syncthreads();
  if (tid < 64) h0p[n * 64 + tid] = f2b(sh[tid]) | (f2b(sh[64 + tid]) << 16);
}

// ---------------- Fused: aggregate L0 + mean-heads + bias + LN + ELU + linear1 + alpha1 ----------------
// one wave per destination node; lane l owns channel l of both heads; weights precomputed

__global__ __launch_bounds__(256) void k_agg0(const int* __restrict__ off,
                                              const uint2* __restrict__ ew,
                                              const uint* __restrict__ h0p,
                                              const float* __restrict__ b0,
                                              const float* __restrict__ lng,
                                              const float* __restrict__ lnb,
                                              const float* __restrict__ W1,
                                              const float* __restrict__ asrc1,
                                              const float* __restrict__ adst1,
                                              ushort* __restrict__ h1b,
                                              float* __restrict__ as1, float* __restrict__ ad1) {
  int n = blockIdx.x * 4 + (threadIdx.x >> 6);
  int lane = threadIdx.x & 63;
  float acc0 = 0.f, acc1 = 0.f, den0 = 0.f, den1 = 0.f;
  int i0 = off[n], i1 = off[n + 1];
  int i = i0;
  for (; i + 3 < i1; i += 4) {
    uint2 rA = ew[i], rB = ew[i + 1], rC = ew[i + 2], rD = ew[i + 3];
    uint hA = h0p[rA.x * 64 + lane];
    uint hB = h0p[rB.x * 64 + lane];
    uint hC = h0p[rC.x * 64 + lane];
    uint hD = h0p[rD.x * 64 + lane];
    float w;
    w = b2f_lo(rA.y); acc0 += w * b2f_lo(hA); den0 += w;
    w = b2f_hi(rA.y); acc1 += w * b2f_hi(hA); den1 += w;
    w = b2f_lo(rB.y); acc0 += w * b2f_lo(hB); den0 += w;
    w = b2f_hi(rB.y); acc1 += w * b2f_hi(hB); den1 += w;
    w = b2f_lo(rC.y); acc0 += w * b2f_lo(hC); den0 += w;
    w = b2f_hi(rC.y); acc1 += w * b2f_hi(hC); den1 += w;
    w = b2f_lo(rD.y); acc0 += w * b2f_lo(hD); den0 += w;
    w = b2f_hi(rD.y); acc1 += w * b2f_hi(hD); den1 += w;
  }
  for (; i < i1; ++i) {
    uint2 r = ew[i];
    uint h = h0p[r.x * 64 + lane];
    float w;
    w = b2f_lo(r.y); acc0 += w * b2f_lo(h); den0 += w;
    w = b2f_hi(r.y); acc1 += w * b2f_hi(h); den1 += w;
  }
  float v = 0.5f * (acc0 / den0 + acc1 / den1) + b0[lane];
  // LayerNorm across the 64 channels (one wave)
  float mu = v;
#pragma unroll
  for (int o = 32; o >= 1; o >>= 1) mu += __shfl_xor(mu, o, 64);
  mu *= (1.0f / 64.0f);
  float d = v - mu;
  float vr = d * d;
#pragma unroll
  for (int o = 32; o >= 1; o >>= 1) vr += __shfl_xor(vr, o, 64);
  vr *= (1.0f / 64.0f);
  float y = d * rsqrtf(vr + 1e-5f) * lng[lane] + lnb[lane];
  // ELU
  y = y > 0.f ? y : expm1f(y);
  // linear1: h1[c] = sum_k y_k * W1[k,c]
  float h1v = 0.f;
#pragma unroll
  for (int k = 0; k < 64; ++k) {
    float yk = __shfl(y, k, 64);
    h1v += yk * W1[k * 64 + lane];
  }
  h1b[n * 64 + lane] = (ushort)f2b(h1v);
  float sa = h1v * asrc1[lane];
  float sdv = h1v * adst1[lane];
#pragma unroll
  for (int o = 32; o >= 1; o >>= 1) {
    sa += __shfl_xor(sa, o, 64);
    sdv += __shfl_xor(sdv, o, 64);
  }
  if (lane == 0) {
    as1[n] = sa;
    ad1[n] = sdv;
  }
}

// ---------------- Layer 1 aggregate -> output (weights inline; as1 is L2-resident) ----------------

__global__ __launch_bounds__(256) void k_agg1(const int* __restrict__ off,
                                              const uint2* __restrict__ ew,
                                              const ushort* __restrict__ h1b,
                                              const float* __restrict__ as1,
                                              const float* __restrict__ ad1,
                                              const float* __restrict__ b1,
                                              float* __restrict__ out) {
  int n = blockIdx.x * 4 + (threadIdx.x >> 6);
  int lane = threadIdx.x & 63;
  float adv = ad1[n];
  float acc = 0.f, den = 0.f;
  int i0 = off[n], i1 = off[n + 1];
  int i = i0;
  for (; i + 3 < i1; i += 4) {
    uint sA = ew[i].x, sB = ew[i + 1].x, sC = ew[i + 2].x, sD = ew[i + 3].x;
    float aA = as1[sA], aB = as1[sB], aC = as1[sC], aD = as1[sD];
    uint hA = h1b[sA * 64 + lane];
    uint hB = h1b[sB * 64 + lane];
    uint hC = h1b[sC * 64 + lane];
    uint hD = h1b[sD * 64 + lane];
    float w;
    w = __expf(lrelu(aA + adv)); acc += w * __uint_as_float(hA << 16); den += w;
    w = __expf(lrelu(aB + adv)); acc += w * __uint_as_float(hB << 16); den += w;
    w = __expf(lrelu(aC + adv)); acc += w * __uint_as_float(hC << 16); den += w;
    w = __expf(lrelu(aD + adv)); acc += w * __uint_as_float(hD << 16); den += w;
  }
  for (; i < i1; ++i) {
    uint s = ew[i].x;
    float w = __expf(lrelu(as1[s] + adv));
    acc += w * __uint_as_float((uint)h1b[s * 64 + lane] << 16);
    den += w;
  }
  out[n * 64 + lane] = acc / den + b1[lane];
}

// ---------------- host ----------------

extern "C" void kernel_launch(void* const* d_in, const int* in_sizes, int n_in,
                              void* d_out, int out_size, void* d_ws, size_t ws_size,
                              hipStream_t stream) {
  const float* x    = (const float*)d_in[0];
  const int*   ei   = (const int*)d_in[1];
  const float* emb  = (const float*)d_in[2];
  const float* W0   = (const float*)d_in[3];
  const float* as0w = (const float*)d_in[4];
  const float* ad0w = (const float*)d_in[5];
  const float* b0   = (const float*)d_in[6];
  const float* lng  = (const float*)d_in[7];
  const float* lnb  = (const float*)d_in[8];
  const float* W1   = (const float*)d_in[9];
  const float* as1w = (const float*)d_in[10];
  const float* ad1w = (const float*)d_in[11];
  const float* b1   = (const float*)d_in[12];
  float* out = (float*)d_out;

  // workspace layout (8B-aligned arrays first); total ~29 MB
  uint2* ew  = (uint2*)d_ws;                  // E_TOT {src, bf16x2 w0|w1}
  float* as0 = (float*)(ew + E_TOT);          // N*2
  float* ad0 = as0 + N_NODES * 2;             // N*2
  float* as1 = ad0 + N_NODES * 2;             // N
  float* ad1 = as1 + N_NODES;                 // N
  uint* h0p = (uint*)(ad1 + N_NODES);         // N*64 (bf16x2 packed)
  ushort* h1b = (ushort*)(h0p + N_NODES * 64);  // N*64 bf16
  int* deg  = (int*)(h1b + N_NODES * 64);     // N
  int* off  = deg + N_NODES;                  // N+1
  int* ofs  = off + N_NODES + 1;              // N
  int* bsum = ofs + N_NODES;                  // 64

  hipMemsetAsync(deg, 0, N_NODES * sizeof(int), stream);
  k_node0<<<N_NODES, 128, 0, stream>>>(x, emb, W0, as0w, ad0w, h0p, as0, ad0);
  k_hist<<<(N_EDGES + 255) / 256, 256, 0, stream>>>(ei, deg);
  k_scan1<<<SCAN_BLOCKS, 1024, 0, stream>>>(deg, off, bsum);
  k_scan23<<<SCAN_BLOCKS, 1024, 0, stream>>>(off, ofs, bsum);
  k_scatter<<<(N_EDGES + N_NODES + 255) / 256, 256, 0, stream>>>(ei, ofs, off, (const float2*)as0,
                                                                 (const float2*)ad0, ew);
  k_agg0<<<N_NODES / 4, 256, 0, stream>>>(off, ew, h0p, b0, lng, lnb, W1, as1w, ad1w,
                                          h1b, as1, ad1);
  k_agg1<<<N_NODES / 4, 256, 0, stream>>>(off, ew, h1b, as1, ad1, b1, out);
}

// Round 6
// 304.713 us; speedup vs baseline: 1.3286x; 1.0443x over previous
//
#include <hip/hip_runtime.h>
#include <hip/hip_bf16.h>

#define N_NODES 50000
#define N_EDGES 800000
#define E_TOT 850000  // edges + self loops, CSR-resident
#define F_IN 32
#define CELL_DIM 16
#define D_IN 48      // F_IN + CELL_DIM
#define X_STRIDE 33  // F_IN + 1 (cell id column)
#define NUM_CELLS 854
#define NEG_SLOPE 0.2f
#define SCAN_BLOCKS 49  // ceil(50000/1024)

typedef unsigned int uint;
typedef unsigned short ushort;

// f32 -> bf16 bits, round-to-nearest-even
static __device__ __forceinline__ uint f2b(float f) {
  uint x = __float_as_uint(f);
  return (x + 0x7fffu + ((x >> 16) & 1u)) >> 16;
}
static __device__ __forceinline__ float b2f_lo(uint w) { return __uint_as_float(w << 16); }
static __device__ __forceinline__ float b2f_hi(uint w) { return __uint_as_float(w & 0xffff0000u); }
static __device__ __forceinline__ float lrelu(float e) { return e > 0.f ? e : NEG_SLOPE * e; }

// ---------------- CSR build ----------------

__global__ __launch_bounds__(256) void k_hist(const int* __restrict__ ei, int* __restrict__ deg) {
  int e = blockIdx.x * 256 + threadIdx.x;
  if (e < N_EDGES) atomicAdd(&deg[ei[N_EDGES + e]], 1);
}

// shfl-based block scan of (deg+1); 2 barriers; bsum[b] = block total (unscanned)
__global__ __launch_bounds__(1024) void k_scan1(const int* __restrict__ deg, int* __restrict__ off,
                                                int* __restrict__ bsum) {
  __shared__ int ws[16];
  int tid = threadIdx.x;
  int lane = tid & 63, wid = tid >> 6;
  int i = blockIdx.x * 1024 + tid;
  int v = (i < N_NODES) ? deg[i] + 1 : 0;  // +1 slot for self-loop
  int sc = v;
#pragma unroll
  for (int o = 1; o < 64; o <<= 1) {
    int t = __shfl_up(sc, o, 64);
    if (lane >= o) sc += t;
  }
  if (lane == 63) ws[wid] = sc;
  __syncthreads();
  if (tid < 16) {
    int w = ws[tid];
    int s = w;
#pragma unroll
    for (int o = 1; o < 16; o <<= 1) {
      int t = __shfl_up(s, o, 64);
      if (tid >= o) s += t;
    }
    ws[tid] = s - w;  // exclusive wave prefix
  }
  __syncthreads();
  int excl = sc - v + ws[wid];
  if (i < N_NODES) off[i] = excl;
  if (tid == 1023) bsum[blockIdx.x] = excl + v;  // block total
}

// fused scan2+scan3: each block re-scans the 49 block sums (cheap), adds its prefix
__global__ __launch_bounds__(1024) void k_scan23(int* __restrict__ off, int* __restrict__ ofs,
                                                 const int* __restrict__ bsum) {
  __shared__ int carry_s;
  int tid = threadIdx.x;
  if (tid < 64) {
    int v = (tid < SCAN_BLOCKS) ? bsum[tid] : 0;
    int s = v;
#pragma unroll
    for (int o = 1; o < 64; o <<= 1) {
      int t = __shfl_up(s, o, 64);
      if (tid >= o) s += t;
    }
    if (tid == (int)blockIdx.x) carry_s = s - v;  // exclusive prefix of this block
  }
  __syncthreads();
  int carry = carry_s;
  int i = blockIdx.x * 1024 + tid;
  if (i < N_NODES) {
    int v = off[i] + carry;
    off[i] = v;
    ofs[i] = v;
  }
  if (i == 0) off[N_NODES] = E_TOT;
}

// scatter edges into CSR slots + compute layer-0 attention weights; tail range fills self-loops
__global__ __launch_bounds__(256) void k_scatter(const int* __restrict__ ei, int* __restrict__ ofs,
                                                 const int* __restrict__ off,
                                                 const float2* __restrict__ as0v,
                                                 const float2* __restrict__ ad0v,
                                                 uint2* __restrict__ ew) {
  int t = blockIdx.x * 256 + threadIdx.x;
  if (t < N_EDGES) {
    int s = ei[t], d = ei[N_EDGES + t];
    float2 a_s = as0v[s], a_d = ad0v[d];
    float w0 = __expf(lrelu(a_s.x + a_d.x));
    float w1 = __expf(lrelu(a_s.y + a_d.y));
    int p = atomicAdd(&ofs[d], 1);
    ew[p] = make_uint2((uint)s, f2b(w0) | (f2b(w1) << 16));
  } else if (t < N_EDGES + N_NODES) {
    int n = t - N_EDGES;  // self-loop record in the reserved last slot
    int slot = off[n + 1] - 1;
    float2 a_s = as0v[n], a_d = ad0v[n];
    float w0 = __expf(lrelu(a_s.x + a_d.x));
    float w1 = __expf(lrelu(a_s.y + a_d.y));
    ew[slot] = make_uint2((uint)n, f2b(w0) | (f2b(w1) << 16));
  }
}

// ---------------- Layer 0 node linear: h0 = [x | emb] @ W0, packed bf16x2 (head0,head1)/channel ----

__global__ __launch_bounds__(128) void k_node0(const float* __restrict__ x,
                                               const float* __restrict__ emb,
                                               const float* __restrict__ W0,
                                               const float* __restrict__ asrc,
                                               const float* __restrict__ adst,
                                               uint* __restrict__ h0p, float* __restrict__ as0,
                                               float* __restrict__ ad0) {
  int n = blockIdx.x;
  int tid = threadIdx.x;
  __shared__ float hin[D_IN];
  __shared__ float sh[128];
  if (tid < F_IN) {
    hin[tid] = x[n * X_STRIDE + tid];
  } else if (tid < D_IN) {
    int cid = (int)x[n * X_STRIDE + F_IN];
    cid = cid < 0 ? 0 : (cid >= NUM_CELLS ? NUM_CELLS - 1 : cid);  // fault guard
    hin[tid] = emb[cid * CELL_DIM + (tid - F_IN)];
  }
  __syncthreads();
  float acc = 0.f;
#pragma unroll
  for (int k = 0; k < D_IN; ++k) acc += hin[k] * W0[k * 128 + tid];
  sh[tid] = acc;
  int head = tid >> 6, lane = tid & 63;
  float sa = acc * asrc[head * 64 + lane];
  float sd = acc * adst[head * 64 + lane];
#pragma unroll
  for (int o = 32; o >= 1; o >>= 1) {
    sa += __shfl_xor(sa, o, 64);
    sd += __shfl_xor(sd, o, 64);
  }
  if (lane == 0) {
    as0[n * 2 + head] = sa;
    ad0[n * 2 + head] = sd;
  }
  __syncthreads();
  if (tid < 64) h0p[n * 64 + tid] = f2b(sh[tid]) | (f2b(sh[64 + tid]) << 16);
}

// ---------------- Fused: aggregate L0 + mean-heads + bias + LN + ELU + linear1 + alpha1 ----------------
// one wave per destination node; lane l owns channel l of both heads; weights precomputed
// edge loop unrolled x8 for memory-level parallelism (VGPR ~56, still 8 waves/SIMD)

__global__ __launch_bounds__(256) void k_agg0(const int* __restrict__ off,
                                              const uint2* __restrict__ ew,
                                              const uint* __restrict__ h0p,
                                              const float* __restrict__ b0,
                                              const float* __restrict__ lng,
                                              const float* __restrict__ lnb,
                                              const float* __restrict__ W1,
                                              const float* __restrict__ asrc1,
                                              const float* __restrict__ adst1,
                                              ushort* __restrict__ h1b,
                                              float* __restrict__ as1, float* __restrict__ ad1) {
  int n = blockIdx.x * 4 + (threadIdx.x >> 6);
  int lane = threadIdx.x & 63;
  float acc0 = 0.f, acc1 = 0.f, den0 = 0.f, den1 = 0.f;
  int i0 = off[n], i1 = off[n + 1];
  int i = i0;
  for (; i + 7 < i1; i += 8) {
    uint2 r[8];
    uint h[8];
#pragma unroll
    for (int j = 0; j < 8; ++j) r[j] = ew[i + j];
#pragma unroll
    for (int j = 0; j < 8; ++j) h[j] = h0p[r[j].x * 64 + lane];
#pragma unroll
    for (int j = 0; j < 8; ++j) {
      float w;
      w = b2f_lo(r[j].y); acc0 += w * b2f_lo(h[j]); den0 += w;
      w = b2f_hi(r[j].y); acc1 += w * b2f_hi(h[j]); den1 += w;
    }
  }
  for (; i + 3 < i1; i += 4) {
    uint2 r[4];
    uint h[4];
#pragma unroll
    for (int j = 0; j < 4; ++j) r[j] = ew[i + j];
#pragma unroll
    for (int j = 0; j < 4; ++j) h[j] = h0p[r[j].x * 64 + lane];
#pragma unroll
    for (int j = 0; j < 4; ++j) {
      float w;
      w = b2f_lo(r[j].y); acc0 += w * b2f_lo(h[j]); den0 += w;
      w = b2f_hi(r[j].y); acc1 += w * b2f_hi(h[j]); den1 += w;
    }
  }
  for (; i < i1; ++i) {
    uint2 r = ew[i];
    uint h = h0p[r.x * 64 + lane];
    float w;
    w = b2f_lo(r.y); acc0 += w * b2f_lo(h); den0 += w;
    w = b2f_hi(r.y); acc1 += w * b2f_hi(h); den1 += w;
  }
  float v = 0.5f * (acc0 / den0 + acc1 / den1) + b0[lane];
  // LayerNorm across the 64 channels (one wave)
  float mu = v;
#pragma unroll
  for (int o = 32; o >= 1; o >>= 1) mu += __shfl_xor(mu, o, 64);
  mu *= (1.0f / 64.0f);
  float d = v - mu;
  float vr = d * d;
#pragma unroll
  for (int o = 32; o >= 1; o >>= 1) vr += __shfl_xor(vr, o, 64);
  vr *= (1.0f / 64.0f);
  float y = d * rsqrtf(vr + 1e-5f) * lng[lane] + lnb[lane];
  // ELU
  y = y > 0.f ? y : expm1f(y);
  // linear1: h1[c] = sum_k y_k * W1[k,c]
  float h1v = 0.f;
#pragma unroll
  for (int k = 0; k < 64; ++k) {
    float yk = __shfl(y, k, 64);
    h1v += yk * W1[k * 64 + lane];
  }
  h1b[n * 64 + lane] = (ushort)f2b(h1v);
  float sa = h1v * asrc1[lane];
  float sdv = h1v * adst1[lane];
#pragma unroll
  for (int o = 32; o >= 1; o >>= 1) {
    sa += __shfl_xor(sa, o, 64);
    sdv += __shfl_xor(sdv, o, 64);
  }
  if (lane == 0) {
    as1[n] = sa;
    ad1[n] = sdv;
  }
}

// ---------------- Layer 1 aggregate -> output (weights inline; as1 is L2-resident) ----------------

__global__ __launch_bounds__(256) void k_agg1(const int* __restrict__ off,
                                              const uint2* __restrict__ ew,
                                              const ushort* __restrict__ h1b,
                                              const float* __restrict__ as1,
                                              const float* __restrict__ ad1,
                                              const float* __restrict__ b1,
                                              float* __restrict__ out) {
  int n = blockIdx.x * 4 + (threadIdx.x >> 6);
  int lane = threadIdx.x & 63;
  float adv = ad1[n];
  float acc = 0.f, den = 0.f;
  int i0 = off[n], i1 = off[n + 1];
  int i = i0;
  for (; i + 7 < i1; i += 8) {
    uint s[8];
    float a[8];
    uint h[8];
#pragma unroll
    for (int j = 0; j < 8; ++j) s[j] = ew[i + j].x;
#pragma unroll
    for (int j = 0; j < 8; ++j) a[j] = as1[s[j]];
#pragma unroll
    for (int j = 0; j < 8; ++j) h[j] = h1b[s[j] * 64 + lane];
#pragma unroll
    for (int j = 0; j < 8; ++j) {
      float w = __expf(lrelu(a[j] + adv));
      acc += w * __uint_as_float(h[j] << 16);
      den += w;
    }
  }
  for (; i + 3 < i1; i += 4) {
    uint s[4];
    float a[4];
    uint h[4];
#pragma unroll
    for (int j = 0; j < 4; ++j) s[j] = ew[i + j].x;
#pragma unroll
    for (int j = 0; j < 4; ++j) a[j] = as1[s[j]];
#pragma unroll
    for (int j = 0; j < 4; ++j) h[j] = h1b[s[j] * 64 + lane];
#pragma unroll
    for (int j = 0; j < 4; ++j) {
      float w = __expf(lrelu(a[j] + adv));
      acc += w * __uint_as_float(h[j] << 16);
      den += w;
    }
  }
  for (; i < i1; ++i) {
    uint s = ew[i].x;
    float w = __expf(lrelu(as1[s] + adv));
    acc += w * __uint_as_float((uint)h1b[s * 64 + lane] << 16);
    den += w;
  }
  out[n * 64 + lane] = acc / den + b1[lane];
}

// ---------------- host ----------------

extern "C" void kernel_launch(void* const* d_in, const int* in_sizes, int n_in,
                              void* d_out, int out_size, void* d_ws, size_t ws_size,
                              hipStream_t stream) {
  const float* x    = (const float*)d_in[0];
  const int*   ei   = (const int*)d_in[1];
  const float* emb  = (const float*)d_in[2];
  const float* W0   = (const float*)d_in[3];
  const float* as0w = (const float*)d_in[4];
  const float* ad0w = (const float*)d_in[5];
  const float* b0   = (const float*)d_in[6];
  const float* lng  = (const float*)d_in[7];
  const float* lnb  = (const float*)d_in[8];
  const float* W1   = (const float*)d_in[9];
  const float* as1w = (const float*)d_in[10];
  const float* ad1w = (const float*)d_in[11];
  const float* b1   = (const float*)d_in[12];
  float* out = (float*)d_out;

  // workspace layout (8B-aligned arrays first); total ~29 MB
  uint2* ew  = (uint2*)d_ws;                  // E_TOT {src, bf16x2 w0|w1}
  float* as0 = (float*)(ew + E_TOT);          // N*2
  float* ad0 = as0 + N_NODES * 2;             // N*2
  float* as1 = ad0 + N_NODES * 2;             // N
  float* ad1 = as1 + N_NODES;                 // N
  uint* h0p = (uint*)(ad1 + N_NODES);         // N*64 (bf16x2 packed)
  ushort* h1b = (ushort*)(h0p + N_NODES * 64);  // N*64 bf16
  int* deg  = (int*)(h1b + N_NODES * 64);     // N
  int* off  = deg + N_NODES;                  // N+1
  int* ofs  = off + N_NODES + 1;              // N
  int* bsum = ofs + N_NODES;                  // 64

  hipMemsetAsync(deg, 0, N_NODES * sizeof(int), stream);
  k_node0<<<N_NODES, 128, 0, stream>>>(x, emb, W0, as0w, ad0w, h0p, as0, ad0);
  k_hist<<<(N_EDGES + 255) / 256, 256, 0, stream>>>(ei, deg);
  k_scan1<<<SCAN_BLOCKS, 1024, 0, stream>>>(deg, off, bsum);
  k_scan23<<<SCAN_BLOCKS, 1024, 0, stream>>>(off, ofs, bsum);
  k_scatter<<<(N_EDGES + N_NODES + 255) / 256, 256, 0, stream>>>(ei, ofs, off, (const float2*)as0,
                                                                 (const float2*)ad0, ew);
  k_agg0<<<N_NODES / 4, 256, 0, stream>>>(off, ew, h0p, b0, lng, lnb, W1, as1w, ad1w,
                                          h1b, as1, ad1);
  k_agg1<<<N_NODES / 4, 256, 0, stream>>>(off, ew, h1b, as1, ad1, b1, out);
}

// Round 7
// 301.712 us; speedup vs baseline: 1.3419x; 1.0099x over previous
//
#include <hip/hip_runtime.h>
#include <hip/hip_bf16.h>

#define N_NODES 50000
#define N_EDGES 800000
#define E_TOT 850000  // edges + self loops, CSR-resident
#define F_IN 32
#define CELL_DIM 16
#define D_IN 48      // F_IN + CELL_DIM
#define X_STRIDE 33  // F_IN + 1 (cell id column)
#define NUM_CELLS 854
#define NEG_SLOPE 0.2f
#define SCAN_BLOCKS 49  // ceil(50000/1024)

typedef unsigned int uint;
typedef unsigned short ushort;

// f32 -> bf16 bits, round-to-nearest-even
static __device__ __forceinline__ uint f2b(float f) {
  uint x = __float_as_uint(f);
  return (x + 0x7fffu + ((x >> 16) & 1u)) >> 16;
}
static __device__ __forceinline__ float b2f_lo(uint w) { return __uint_as_float(w << 16); }
static __device__ __forceinline__ float b2f_hi(uint w) { return __uint_as_float(w & 0xffff0000u); }
static __device__ __forceinline__ float lrelu(float e) { return e > 0.f ? e : NEG_SLOPE * e; }

// ---------------- CSR build ----------------

__global__ __launch_bounds__(256) void k_hist(const int* __restrict__ ei, int* __restrict__ deg) {
  int e = blockIdx.x * 256 + threadIdx.x;
  if (e < N_EDGES) atomicAdd(&deg[ei[N_EDGES + e]], 1);
}

// shfl-based block scan of (deg+1); 2 barriers; bsum[b] = block total (unscanned)
__global__ __launch_bounds__(1024) void k_scan1(const int* __restrict__ deg, int* __restrict__ off,
                                                int* __restrict__ bsum) {
  __shared__ int ws[16];
  int tid = threadIdx.x;
  int lane = tid & 63, wid = tid >> 6;
  int i = blockIdx.x * 1024 + tid;
  int v = (i < N_NODES) ? deg[i] + 1 : 0;  // +1 slot for self-loop
  int sc = v;
#pragma unroll
  for (int o = 1; o < 64; o <<= 1) {
    int t = __shfl_up(sc, o, 64);
    if (lane >= o) sc += t;
  }
  if (lane == 63) ws[wid] = sc;
  __syncthreads();
  if (tid < 16) {
    int w = ws[tid];
    int s = w;
#pragma unroll
    for (int o = 1; o < 16; o <<= 1) {
      int t = __shfl_up(s, o, 64);
      if (tid >= o) s += t;
    }
    ws[tid] = s - w;  // exclusive wave prefix
  }
  __syncthreads();
  int excl = sc - v + ws[wid];
  if (i < N_NODES) off[i] = excl;
  if (tid == 1023) bsum[blockIdx.x] = excl + v;  // block total
}

// fused scan2+scan3: each block re-scans the 49 block sums (cheap), adds its prefix
__global__ __launch_bounds__(1024) void k_scan23(int* __restrict__ off, int* __restrict__ ofs,
                                                 const int* __restrict__ bsum) {
  __shared__ int carry_s;
  int tid = threadIdx.x;
  if (tid < 64) {
    int v = (tid < SCAN_BLOCKS) ? bsum[tid] : 0;
    int s = v;
#pragma unroll
    for (int o = 1; o < 64; o <<= 1) {
      int t = __shfl_up(s, o, 64);
      if (tid >= o) s += t;
    }
    if (tid == (int)blockIdx.x) carry_s = s - v;  // exclusive prefix of this block
  }
  __syncthreads();
  int carry = carry_s;
  int i = blockIdx.x * 1024 + tid;
  if (i < N_NODES) {
    int v = off[i] + carry;
    off[i] = v;
    ofs[i] = v;
  }
  if (i == 0) off[N_NODES] = E_TOT;
}

// scatter edges into CSR slots + compute layer-0 attention weights; tail range fills self-loops
__global__ __launch_bounds__(256) void k_scatter(const int* __restrict__ ei, int* __restrict__ ofs,
                                                 const int* __restrict__ off,
                                                 const float2* __restrict__ as0v,
                                                 const float2* __restrict__ ad0v,
                                                 uint2* __restrict__ ew) {
  int t = blockIdx.x * 256 + threadIdx.x;
  if (t < N_EDGES) {
    int s = ei[t], d = ei[N_EDGES + t];
    float2 a_s = as0v[s], a_d = ad0v[d];
    float w0 = __expf(lrelu(a_s.x + a_d.x));
    float w1 = __expf(lrelu(a_s.y + a_d.y));
    int p = atomicAdd(&ofs[d], 1);
    ew[p] = make_uint2((uint)s, f2b(w0) | (f2b(w1) << 16));
  } else if (t < N_EDGES + N_NODES) {
    int n = t - N_EDGES;  // self-loop record in the reserved last slot
    int slot = off[n + 1] - 1;
    float2 a_s = as0v[n], a_d = ad0v[n];
    float w0 = __expf(lrelu(a_s.x + a_d.x));
    float w1 = __expf(lrelu(a_s.y + a_d.y));
    ew[slot] = make_uint2((uint)n, f2b(w0) | (f2b(w1) << 16));
  }
}

// ---------------- Layer 0 node linear: h0 = [x | emb] @ W0, packed bf16x2 (head0,head1)/channel ----

__global__ __launch_bounds__(128) void k_node0(const float* __restrict__ x,
                                               const float* __restrict__ emb,
                                               const float* __restrict__ W0,
                                               const float* __restrict__ asrc,
                                               const float* __restrict__ adst,
                                               uint* __restrict__ h0p, float* __restrict__ as0,
                                               float* __restrict__ ad0) {
  int n = blockIdx.x;
  int tid = threadIdx.x;
  __shared__ float hin[D_IN];
  __shared__ float sh[128];
  if (tid < F_IN) {
    hin[tid] = x[n * X_STRIDE + tid];
  } else if (tid < D_IN) {
    int cid = (int)x[n * X_STRIDE + F_IN];
    cid = cid < 0 ? 0 : (cid >= NUM_CELLS ? NUM_CELLS - 1 : cid);  // fault guard
    hin[tid] = emb[cid * CELL_DIM + (tid - F_IN)];
  }
  __syncthreads();
  float acc = 0.f;
#pragma unroll
  for (int k = 0; k < D_IN; ++k) acc += hin[k] * W0[k * 128 + tid];
  sh[tid] = acc;
  int head = tid >> 6, lane = tid & 63;
  float sa = acc * asrc[head * 64 + lane];
  float sd = acc * adst[head * 64 + lane];
#pragma unroll
  for (int o = 32; o >= 1; o >>= 1) {
    sa += __shfl_xor(sa, o, 64);
    sd += __shfl_xor(sd, o, 64);
  }
  if (lane == 0) {
    as0[n * 2 + head] = sa;
    ad0[n * 2 + head] = sd;
  }
  __syncthreads();
  if (tid < 64) h0p[n * 64 + tid] = f2b(sh[tid]) | (f2b(sh[64 + tid]) << 16);
}

// ---------------- Fused: aggregate L0 + mean-heads + bias + LN + ELU + linear1 + alpha1 ----------------
// one wave per destination node; lane l owns channel l of both heads; weights precomputed
// edge loop unrolled x8; launch_bounds(256,4) caps VGPR at 128 so all 8 gathers stay in flight

__global__ __launch_bounds__(256, 4) void k_agg0(const int* __restrict__ off,
                                              const uint2* __restrict__ ew,
                                              const uint* __restrict__ h0p,
                                              const float* __restrict__ b0,
                                              const float* __restrict__ lng,
                                              const float* __restrict__ lnb,
                                              const float* __restrict__ W1,
                                              const float* __restrict__ asrc1,
                                              const float* __restrict__ adst1,
                                              ushort* __restrict__ h1b,
                                              float* __restrict__ as1, float* __restrict__ ad1) {
  int n = blockIdx.x * 4 + (threadIdx.x >> 6);
  int lane = threadIdx.x & 63;
  float acc0 = 0.f, acc1 = 0.f, den0 = 0.f, den1 = 0.f;
  int i0 = off[n], i1 = off[n + 1];
  int i = i0;
  for (; i + 7 < i1; i += 8) {
    uint2 r[8];
    uint h[8];
#pragma unroll
    for (int j = 0; j < 8; ++j) r[j] = ew[i + j];
#pragma unroll
    for (int j = 0; j < 8; ++j) h[j] = h0p[r[j].x * 64 + lane];
#pragma unroll
    for (int j = 0; j < 8; ++j) {
      float w;
      w = b2f_lo(r[j].y); acc0 += w * b2f_lo(h[j]); den0 += w;
      w = b2f_hi(r[j].y); acc1 += w * b2f_hi(h[j]); den1 += w;
    }
  }
  for (; i + 3 < i1; i += 4) {
    uint2 r[4];
    uint h[4];
#pragma unroll
    for (int j = 0; j < 4; ++j) r[j] = ew[i + j];
#pragma unroll
    for (int j = 0; j < 4; ++j) h[j] = h0p[r[j].x * 64 + lane];
#pragma unroll
    for (int j = 0; j < 4; ++j) {
      float w;
      w = b2f_lo(r[j].y); acc0 += w * b2f_lo(h[j]); den0 += w;
      w = b2f_hi(r[j].y); acc1 += w * b2f_hi(h[j]); den1 += w;
    }
  }
  for (; i < i1; ++i) {
    uint2 r = ew[i];
    uint h = h0p[r.x * 64 + lane];
    float w;
    w = b2f_lo(r.y); acc0 += w * b2f_lo(h); den0 += w;
    w = b2f_hi(r.y); acc1 += w * b2f_hi(h); den1 += w;
  }
  float v = 0.5f * (acc0 / den0 + acc1 / den1) + b0[lane];
  // LayerNorm across the 64 channels (one wave)
  float mu = v;
#pragma unroll
  for (int o = 32; o >= 1; o >>= 1) mu += __shfl_xor(mu, o, 64);
  mu *= (1.0f / 64.0f);
  float d = v - mu;
  float vr = d * d;
#pragma unroll
  for (int o = 32; o >= 1; o >>= 1) vr += __shfl_xor(vr, o, 64);
  vr *= (1.0f / 64.0f);
  float y = d * rsqrtf(vr + 1e-5f) * lng[lane] + lnb[lane];
  // ELU
  y = y > 0.f ? y : expm1f(y);
  // linear1: h1[c] = sum_k y_k * W1[k,c]
  float h1v = 0.f;
#pragma unroll
  for (int k = 0; k < 64; ++k) {
    float yk = __shfl(y, k, 64);
    h1v += yk * W1[k * 64 + lane];
  }
  h1b[n * 64 + lane] = (ushort)f2b(h1v);
  float sa = h1v * asrc1[lane];
  float sdv = h1v * adst1[lane];
#pragma unroll
  for (int o = 32; o >= 1; o >>= 1) {
    sa += __shfl_xor(sa, o, 64);
    sdv += __shfl_xor(sdv, o, 64);
  }
  if (lane == 0) {
    as1[n] = sa;
    ad1[n] = sdv;
  }
}

// ---------------- Layer 1 aggregate -> output (weights inline; as1 is L2-resident) ----------------

__global__ __launch_bounds__(256, 4) void k_agg1(const int* __restrict__ off,
                                              const uint2* __restrict__ ew,
                                              const ushort* __restrict__ h1b,
                                              const float* __restrict__ as1,
                                              const float* __restrict__ ad1,
                                              const float* __restrict__ b1,
                                              float* __restrict__ out) {
  int n = blockIdx.x * 4 + (threadIdx.x >> 6);
  int lane = threadIdx.x & 63;
  float adv = ad1[n];
  float acc = 0.f, den = 0.f;
  int i0 = off[n], i1 = off[n + 1];
  int i = i0;
  for (; i + 7 < i1; i += 8) {
    uint s[8];
    float a[8];
    uint h[8];
#pragma unroll
    for (int j = 0; j < 8; ++j) s[j] = ew[i + j].x;
#pragma unroll
    for (int j = 0; j < 8; ++j) a[j] = as1[s[j]];
#pragma unroll
    for (int j = 0; j < 8; ++j) h[j] = h1b[s[j] * 64 + lane];
#pragma unroll
    for (int j = 0; j < 8; ++j) {
      float w = __expf(lrelu(a[j] + adv));
      acc += w * __uint_as_float(h[j] << 16);
      den += w;
    }
  }
  for (; i + 3 < i1; i += 4) {
    uint s[4];
    float a[4];
    uint h[4];
#pragma unroll
    for (int j = 0; j < 4; ++j) s[j] = ew[i + j].x;
#pragma unroll
    for (int j = 0; j < 4; ++j) a[j] = as1[s[j]];
#pragma unroll
    for (int j = 0; j < 4; ++j) h[j] = h1b[s[j] * 64 + lane];
#pragma unroll
    for (int j = 0; j < 4; ++j) {
      float w = __expf(lrelu(a[j] + adv));
      acc += w * __uint_as_float(h[j] << 16);
      den += w;
    }
  }
  for (; i < i1; ++i) {
    uint s = ew[i].x;
    float w = __expf(lrelu(as1[s] + adv));
    acc += w * __uint_as_float((uint)h1b[s * 64 + lane] << 16);
    den += w;
  }
  out[n * 64 + lane] = acc / den + b1[lane];
}

// ---------------- host ----------------

extern "C" void kernel_launch(void* const* d_in, const int* in_sizes, int n_in,
                              void* d_out, int out_size, void* d_ws, size_t ws_size,
                              hipStream_t stream) {
  const float* x    = (const float*)d_in[0];
  const int*   ei   = (const int*)d_in[1];
  const float* emb  = (const float*)d_in[2];
  const float* W0   = (const float*)d_in[3];
  const float* as0w = (const float*)d_in[4];
  const float* ad0w = (const float*)d_in[5];
  const float* b0   = (const float*)d_in[6];
  const float* lng  = (const float*)d_in[7];
  const float* lnb  = (const float*)d_in[8];
  const float* W1   = (const float*)d_in[9];
  const float* as1w = (const float*)d_in[10];
  const float* ad1w = (const float*)d_in[11];
  const float* b1   = (const float*)d_in[12];
  float* out = (float*)d_out;

  // workspace layout (8B-aligned arrays first); total ~29 MB
  uint2* ew  = (uint2*)d_ws;                  // E_TOT {src, bf16x2 w0|w1}
  float* as0 = (float*)(ew + E_TOT);          // N*2
  float* ad0 = as0 + N_NODES * 2;             // N*2
  float* as1 = ad0 + N_NODES * 2;             // N
  float* ad1 = as1 + N_NODES;                 // N
  uint* h0p = (uint*)(ad1 + N_NODES);         // N*64 (bf16x2 packed)
  ushort* h1b = (ushort*)(h0p + N_NODES * 64);  // N*64 bf16
  int* deg  = (int*)(h1b + N_NODES * 64);     // N
  int* off  = deg + N_NODES;                  // N+1
  int* ofs  = off + N_NODES + 1;              // N
  int* bsum = ofs + N_NODES;                  // 64

  hipMemsetAsync(deg, 0, N_NODES * sizeof(int), stream);
  k_node0<<<N_NODES, 128, 0, stream>>>(x, emb, W0, as0w, ad0w, h0p, as0, ad0);
  k_hist<<<(N_EDGES + 255) / 256, 256, 0, stream>>>(ei, deg);
  k_scan1<<<SCAN_BLOCKS, 1024, 0, stream>>>(deg, off, bsum);
  k_scan23<<<SCAN_BLOCKS, 1024, 0, stream>>>(off, ofs, bsum);
  k_scatter<<<(N_EDGES + N_NODES + 255) / 256, 256, 0, stream>>>(ei, ofs, off, (const float2*)as0,
                                                                 (const float2*)ad0, ew);
  k_agg0<<<N_NODES / 4, 256, 0, stream>>>(off, ew, h0p, b0, lng, lnb, W1, as1w, ad1w,
                                          h1b, as1, ad1);
  k_agg1<<<N_NODES / 4, 256, 0, stream>>>(off, ew, h1b, as1, ad1, b1, out);
}